// Round 2
// baseline (710.317 us; speedup 1.0000x reference)
//
#include <hip/hip_runtime.h>
#include <cstdint>

#define BSZ 32
#define NVIS 1024
#define HID 256
#define TOKD 768
#define NCODE 2048
#define NPIX 32768

typedef unsigned short u16;
typedef _Float16 half8 __attribute__((ext_vector_type(8)));
typedef unsigned short ushort8 __attribute__((ext_vector_type(8)));
using f32x4 = __attribute__((ext_vector_type(4))) float;

#define AS1 __attribute__((address_space(1)))
#define AS3 __attribute__((address_space(3)))

__device__ __forceinline__ f32x4 mfmaF16(half8 a, half8 b, f32x4 c) {
  return __builtin_amdgcn_mfma_f32_16x16x32_f16(a, b, c, 0, 0, 0);
}

__device__ __forceinline__ unsigned long long pack_key(float d, int idx) {
  unsigned int b = __float_as_uint(d);
  b = (b & 0x80000000u) ? ~b : (b | 0x80000000u);  // monotonic float->uint
  return ((unsigned long long)b << 32) | (unsigned int)idx;
}

__device__ __forceinline__ void split16(float v, u16& h, u16& l) {
  union { _Float16 f; u16 u; } a, b;
  a.f = (_Float16)v;
  float hf = (float)a.f;
  b.f = (_Float16)(v - hf);
  h = a.u; l = b.u;
}

// ================= prep1: all weights-only precompute, one launch =================
__global__ __launch_bounds__(256)
void prep1(const float* __restrict__ cb, const float* __restrict__ wh,
           const float* __restrict__ wt, const float* __restrict__ wp,
           const float* __restrict__ wg, const float* __restrict__ bp,
           u16* __restrict__ cbh, u16* __restrict__ cbl,
           u16* __restrict__ whh, u16* __restrict__ whl,
           float* __restrict__ cbn, float* __restrict__ Mm, float* __restrict__ uv,
           float* __restrict__ Gt, float* __restrict__ g2,
           float* __restrict__ ct0, float* __restrict__ cg) {
  const int bid = blockIdx.x, tid = threadIdx.x;
  if (bid < 6144) {                       // split cb
    int i = bid*256 + tid;
    u16 h, l; split16(cb[i], h, l);
    cbh[i] = h; cbl[i] = l;
  } else if (bid < 6912) {                // split w_head
    int i = (bid - 6144)*256 + tid;
    u16 h, l; split16(wh[i], h, l);
    whh[i] = h; whl[i] = l;
  } else if (bid < 7424) {                // code norms
    int n = (bid - 6912)*4 + (tid >> 6);
    int lane = tid & 63;
    float a = 0.f;
#pragma unroll
    for (int i = 0; i < 12; ++i) { float v = cb[(long)n*TOKD + lane + 64*i]; a += v*v; }
#pragma unroll
    for (int off = 32; off; off >>= 1) a += __shfl_down(a, off);
    if (lane == 0) cbn[n] = a;
  } else if (bid < 7680) {                // make_M
    int c2 = bid - 7424, c1 = tid;
    float acc = 0.f;
    for (int t = 0; t < TOKD; ++t) acc += wh[t*HID + c1] * wt[(long)c2*TOKD + t];
    Mm[c1*HID + c2] = acc;
  } else if (bid < 7682) {                // make_u
    int o = bid - 7680, c1 = tid;
    float acc = 0.f;
    for (int t = 0; t < TOKD; ++t) acc += wh[t*HID + c1] * wg[o*(2*TOKD) + TOKD + t];
    uv[o*HID + c1] = acc;
  } else if (bid < 8450) {                // make_Gt
    int rbid = bid - 7682;
    int c = rbid & 255, part = rbid >> 8;
    int tp = part*256 + tid;
    float acc = 0.f;
    for (int t = 0; t < TOKD; ++t) acc += wt[(long)c*TOKD + t] * wp[(long)t*TOKD + tp];
    Gt[(long)tp*HID + c] = acc;
  } else if (bid < 8453) {                // g2
    int tp = (bid - 8450)*256 + tid;
    float a0 = 0.f, a1 = 0.f;
    for (int t = 0; t < TOKD; ++t) {
      float wv = wp[(long)t*TOKD + tp];
      a0 += wv * wg[t];
      a1 += wv * wg[2*TOKD + t];
    }
    g2[tp] = a0; g2[TOKD + tp] = a1;
  } else if (bid < 8454) {                // ct0
    int c = tid;
    float a = 0.f;
    for (int t = 0; t < TOKD; ++t) a += bp[t] * wt[(long)c*TOKD + t];
    ct0[c] = a;
  } else {                                // cg
    int o = tid >> 6, lane = tid & 63;
    if (o < 2) {
      float a = 0.f;
      for (int t = lane; t < TOKD; t += 64) a += bp[t] * wg[o*(2*TOKD) + t];
#pragma unroll
      for (int off = 32; off; off >>= 1) a += __shfl_down(a, off);
      if (lane == 0) cg[o] = a;
    }
  }
}

// ================= prep2: tailcode + gA from shared cb tile =================
__global__ __launch_bounds__(256)
void prep2(const float* __restrict__ cb, const float* __restrict__ Gt,
           const float* __restrict__ ct0, const float* __restrict__ g2,
           const float* __restrict__ cg, float* __restrict__ tc,
           float* __restrict__ gA) {
  __shared__ float cbs[8][TOKD];
  const int n0 = blockIdx.x * 8, tid = threadIdx.x;
  for (int i = tid; i < 8*TOKD; i += 256) cbs[i / TOKD][i % TOKD] = cb[(long)n0*TOKD + i];
  __syncthreads();
  float acc[8] = {};
  for (int t = 0; t < TOKD; ++t) {
    float gv = Gt[(long)t*HID + tid];
#pragma unroll
    for (int i = 0; i < 8; ++i) acc[i] += cbs[i][t] * gv;
  }
  float c0v = ct0[tid];
#pragma unroll
  for (int i = 0; i < 8; ++i) tc[(long)(n0+i)*HID + tid] = acc[i] + c0v;
  {
    int i = tid >> 5, l32 = tid & 31;
    float a0 = 0.f, a1 = 0.f;
    for (int t = l32; t < TOKD; t += 32) {
      float cv = cbs[i][t];
      a0 += cv * g2[t];
      a1 += cv * g2[TOKD + t];
    }
#pragma unroll
    for (int off = 16; off; off >>= 1) { a0 += __shfl_down(a0, off); a1 += __shfl_down(a1, off); }
    if (l32 == 0) { gA[n0+i] = a0 + cg[0]; gA[NCODE + n0+i] = a1 + cg[1]; }
  }
}

// ================= head GEMM (round-4 verified, row-major coalesced stores) =================
__global__ __launch_bounds__(256)
void head_mfma(const u16* __restrict__ whh, const u16* __restrict__ whl,
               const float* __restrict__ src,
               u16* __restrict__ xqh, u16* __restrict__ xql) {
  __shared__ u16 SM[32768] __attribute__((aligned(16)));   // 64 KB
  u16* Ah = SM;            // [2][4096]
  u16* Al = SM + 8192;
  u16* Bh = SM + 16384;
  u16* Bl = SM + 24576;
  const int tid = threadIdx.x, lane = tid & 63, w = tid >> 6;
  const int n = lane & 15, q = lane >> 4;
  const int rh = w & 1, ch = w >> 1;
  const int obase = blockIdx.x * 128, pbase = blockIdx.y * 128, b = blockIdx.z;

  auto stageA = [&](int kc, int buf) {
#pragma unroll
    for (int is = 0; is < 2; ++is) {
      int c = is*256 + tid;
      int t = c >> 6, qq = (c >> 4) & 3, nn = c & 15;
      long off = (long)(obase + t*16 + nn)*HID + kc*32 + qq*8;
      __builtin_amdgcn_global_load_lds((AS1 void*)(whh + off),
          (AS3 void*)&Ah[buf*4096 + c*8], 16, 0, 0);
      __builtin_amdgcn_global_load_lds((AS1 void*)(whl + off),
          (AS3 void*)&Al[buf*4096 + c*8], 16, 0, 0);
    }
  };
  auto stageB = [&](int kc, int buf) {
#pragma unroll
    for (int is = 0; is < 2; ++is) {
      int c = is*256 + tid;
      int t = c >> 6, qq = (c >> 4) & 3, nn = c & 15;
      const float* gp = src + ((long)(pbase + t*16 + nn)*BSZ + b)*HID + kc*32 + qq*8;
      float4 v0 = *(const float4*)gp;
      float4 v1 = *(const float4*)(gp + 4);
      float vv[8] = {v0.x, v0.y, v0.z, v0.w, v1.x, v1.y, v1.z, v1.w};
      ushort8 hv, lv;
#pragma unroll
      for (int j = 0; j < 8; ++j) { u16 hs, ls; split16(vv[j], hs, ls); hv[j] = hs; lv[j] = ls; }
      *(ushort8*)&Bh[buf*4096 + c*8] = hv;
      *(ushort8*)&Bl[buf*4096 + c*8] = lv;
    }
  };

  f32x4 acc[4][4];
#pragma unroll
  for (int i = 0; i < 4; ++i)
#pragma unroll
    for (int j = 0; j < 4; ++j) acc[i][j] = (f32x4){0.f, 0.f, 0.f, 0.f};

  stageA(0, 0); stageB(0, 0);
  __syncthreads();

  for (int kt = 0; kt < HID/32; ++kt) {
    const int buf = kt & 1;
    if (kt + 1 < HID/32) { stageA(kt + 1, buf ^ 1); stageB(kt + 1, buf ^ 1); }
    half8 af[4][2], bf[4][2];
#pragma unroll
    for (int rt = 0; rt < 4; ++rt) {
      int idx = buf*4096 + ((rh*4 + rt)*64 + q*16 + n)*8;
      af[rt][0] = *(const half8*)&Ah[idx];
      af[rt][1] = *(const half8*)&Al[idx];
    }
#pragma unroll
    for (int ct = 0; ct < 4; ++ct) {
      int idx = buf*4096 + ((ch*4 + ct)*64 + q*16 + n)*8;
      bf[ct][0] = *(const half8*)&Bh[idx];
      bf[ct][1] = *(const half8*)&Bl[idx];
    }
#pragma unroll
    for (int rt = 0; rt < 4; ++rt)
#pragma unroll
      for (int ct = 0; ct < 4; ++ct) {
        acc[rt][ct] = mfmaF16(af[rt][0], bf[ct][0], acc[rt][ct]);
        acc[rt][ct] = mfmaF16(af[rt][0], bf[ct][1], acc[rt][ct]);
        acc[rt][ct] = mfmaF16(af[rt][1], bf[ct][0], acc[rt][ct]);
      }
    __syncthreads();
  }

#pragma unroll
  for (int pass = 0; pass < 2; ++pass) {
    u16* dst = pass ? xql : xqh;
#pragma unroll
    for (int rt = 0; rt < 4; ++rt)
#pragma unroll
      for (int ct = 0; ct < 4; ++ct)
#pragma unroll
        for (int reg = 0; reg < 4; ++reg) {
          u16 hs, ls; split16(acc[rt][ct][reg], hs, ls);
          int ol = rh*64 + rt*16 + q*4 + reg;
          int pl = ch*64 + ct*16 + n;
          SM[ol*136 + pl] = pass ? ls : hs;
        }
    __syncthreads();
#pragma unroll
    for (int s = 0; s < 8; ++s) {
      int cc = tid*8 + s;
      int o = cc >> 4, p8 = cc & 15;
      ushort8 v = *(const ushort8*)&SM[o*136 + p8*8];
      *(ushort8*)(dst + ((long)b*TOKD + obase + o)*NVIS + pbase + p8*8) = v;
    }
    __syncthreads();
  }
}

// ================= retile: in-place row-major -> MFMA-fragment-tiled =================
__global__ __launch_bounds__(256)
void retile(u16* __restrict__ bufH, u16* __restrict__ bufL) {
  __shared__ u16 T[96*136] __attribute__((aligned(16)));
  const long tile = blockIdx.x;
  const int tid = threadIdx.x;
#pragma unroll
  for (int pass = 0; pass < 2; ++pass) {
    u16* buf = pass ? bufL : bufH;
    if (pass) __syncthreads();
#pragma unroll
    for (int i = 0; i < 6; ++i) {
      int g = i*256 + tid;
      int row = g / 96, c16 = g % 96;
      ushort8 v = *(const ushort8*)(buf + tile*12288 + row*768 + c16*8);
      *(ushort8*)&T[c16*136 + row*8] = v;
    }
    __syncthreads();
#pragma unroll
    for (int i = 0; i < 6; ++i) {
      int g = i*256 + tid;
      int kc = g >> 6, lp = g & 63;
      int q = lp >> 4, n = lp & 15;
      ushort8 v = *(const ushort8*)&T[(kc*4 + q)*136 + n*8];
      *(ushort8*)(buf + tile*12288 + (long)kc*512 + lp*8) = v;
    }
  }
}

// ================= VQ: 256x256 LDS-staged MFMA, ds_read||MFMA overlap + XCD row-partition ===
// Mapping: xcd = bid&7 owns rows [xcd*4096, (xcd+1)*4096); within XCD, codeBlk = slot&7
// cycles fastest -> 32 concurrent blocks/XCD = 4 rowBlks x 8 codeBlks: A working set 3.1 MB
// (L2-resident, each A slice filled ONCE per XCD ~= 100 MB total) while B (6.3 MB, L3-hot)
// streams 4x/XCD (~200 MB). Predicted FETCH_SIZE ~300 MB (was 608).
// Iter structure (T3+T4+T5): STAGE(ht+3) -> vmcnt(8) -> barrier (all waves' tile ht+1 in LDS)
// -> [ds_read frags(ht+1) || 32 MFMA on frags(ht)] -> lgkmcnt(0) -> barrier.
// Named F0/F1 fragment sets (manual 2x unroll, rule #20: no runtime-indexed reg arrays).
// Buffer safety: buf (ht+1)&3 rewritten at iter ht+2's STAGE, two barriers after the reads.
// vmcnt invariant: at iter top 8 outstanding (tiles ht+1,ht+2); +4 staged; vmcnt(8) drains
// exactly tile ht+1. Tail keeps the count uniform by dup-staging tile 71 into dead bufs.
__global__ __launch_bounds__(512, 2)
void vq_mfma(const u16* __restrict__ xqh, const u16* __restrict__ xql,
             const u16* __restrict__ cbh, const u16* __restrict__ cbl,
             const float* __restrict__ cbn, unsigned long long* __restrict__ keys) {
  __shared__ u16 SM[65536] __attribute__((aligned(16)));   // 128 KB: A[4][8192] | B[4][8192]
  const int bid = blockIdx.x;
  const int xcd = bid & 7, slot = bid >> 3;
  const int rowBlk = xcd * 16 + (slot >> 3);   // 0..127, XCD-partitioned rows
  const int codeBlk = slot & 7;                // 0..7, fastest-cycling within XCD
  const int rowTile0 = rowBlk * 16, codeTile0 = codeBlk * 16;
  const int tid = threadIdx.x, lane = tid & 63, w = tid >> 6;
  const int n = lane & 15, q = lane >> 4;
  const int wr = w >> 2, wc = w & 3;

  // per-wave staging chunk pair: tiles {2w, 2w+1} of the block's 16 row-tiles / code-tiles
  const size_t aOff = (size_t)(rowTile0 + 2*w) * 12288 + lane*8;
  const size_t bOff = (size_t)(codeTile0 + 2*w) * 12288 + lane*8;
  const int ldsChunk = (2*w)*512 + lane*8;   // u16 units within a 16 KB buffer

  auto STAGE = [&](int ht, int buf) {
    const int seg = (ht >= 48) ? 2 : ((ht >= 24) ? 1 : 0);
    const int kk = ht - seg * 24;
    const u16* pa = ((seg == 1) ? xql : xqh) + aOff + kk*512;
    const u16* pb = ((seg == 2) ? cbl : cbh) + bOff + kk*512;
    u16* la = &SM[buf*8192 + ldsChunk];
    u16* lb = &SM[32768 + buf*8192 + ldsChunk];
    __builtin_amdgcn_global_load_lds((AS1 void*)pa,           (AS3 void*)la,        16, 0, 0);
    __builtin_amdgcn_global_load_lds((AS1 void*)(pa + 12288), (AS3 void*)(la + 512), 16, 0, 0);
    __builtin_amdgcn_global_load_lds((AS1 void*)pb,           (AS3 void*)lb,        16, 0, 0);
    __builtin_amdgcn_global_load_lds((AS1 void*)(pb + 12288), (AS3 void*)(lb + 512), 16, 0, 0);
  };

  f32x4 acc[8][4];
#pragma unroll
  for (int a = 0; a < 8; ++a)
#pragma unroll
    for (int b2 = 0; b2 < 4; ++b2) acc[a][b2] = (f32x4){0.f, 0.f, 0.f, 0.f};

  half8 F0A[8], F0B[4], F1A[8], F1B[4];

  STAGE(0, 0); STAGE(1, 1); STAGE(2, 2);   // prologue: 12 loads in flight
  asm volatile("s_waitcnt vmcnt(8)" ::: "memory");   // tile 0 landed (all 4 of my loads)
  asm volatile("s_barrier" ::: "memory");            // ... for every wave
  {
    const int ab = (wr*8)*512 + lane*8;
    const int bb = 32768 + (wc*4)*512 + lane*8;
#pragma unroll
    for (int rt = 0; rt < 8; ++rt) F0A[rt] = *(const half8*)&SM[ab + rt*512];
#pragma unroll
    for (int ct = 0; ct < 4; ++ct) F0B[ct] = *(const half8*)&SM[bb + ct*512];
  }

#define VQ_ITER(HT, CA, CB, NA, NB, DO_READ)                               \
  {                                                                        \
    const int ht_ = (HT);                                                  \
    const int pf_ = (ht_ + 3 > 71) ? 71 : ht_ + 3;                         \
    STAGE(pf_, (ht_ + 3) & 3);                                             \
    asm volatile("s_waitcnt vmcnt(8)" ::: "memory");                       \
    asm volatile("s_barrier" ::: "memory");                                \
    if (DO_READ) {                                                         \
      const int b1_ = (ht_ + 1) & 3;                                       \
      const int ab_ = b1_*8192 + (wr*8)*512 + lane*8;                      \
      const int bb_ = 32768 + b1_*8192 + (wc*4)*512 + lane*8;              \
      _Pragma("unroll")                                                    \
      for (int rt = 0; rt < 8; ++rt) NA[rt] = *(const half8*)&SM[ab_ + rt*512]; \
      _Pragma("unroll")                                                    \
      for (int ct = 0; ct < 4; ++ct) NB[ct] = *(const half8*)&SM[bb_ + ct*512]; \
    }                                                                      \
    __builtin_amdgcn_s_setprio(1);                                         \
    _Pragma("unroll")                                                      \
    for (int rt = 0; rt < 8; ++rt)                                         \
      _Pragma("unroll")                                                    \
      for (int ct = 0; ct < 4; ++ct)                                       \
        acc[rt][ct] = mfmaF16(CA[rt], CB[ct], acc[rt][ct]);                \
    __builtin_amdgcn_s_setprio(0);                                         \
    asm volatile("s_waitcnt lgkmcnt(0)" ::: "memory");                     \
    asm volatile("s_barrier" ::: "memory");                                \
  }

#pragma unroll 1
  for (int h2 = 0; h2 < 35; ++h2) {
    VQ_ITER(2*h2,     F0A, F0B, F1A, F1B, 1);
    VQ_ITER(2*h2 + 1, F1A, F1B, F0A, F0B, 1);
  }
  VQ_ITER(70, F0A, F0B, F1A, F1B, 1);
  VQ_ITER(71, F1A, F1B, F0A, F0B, 0);
#undef VQ_ITER

  // argmin epilogue: lane holds (row = rt*16 + q*4 + reg, code = ct*16 + n) in wave tiles
  float cbv[4];
#pragma unroll
  for (int ct = 0; ct < 4; ++ct) cbv[ct] = cbn[(codeTile0 + wc*4 + ct)*16 + n];
#pragma unroll
  for (int rt = 0; rt < 8; ++rt) {
#pragma unroll
    for (int reg = 0; reg < 4; ++reg) {
      float bd = 3.4e38f; int bi = 0;
#pragma unroll
      for (int ct = 0; ct < 4; ++ct) {
        float d = cbv[ct] - 2.0f * acc[rt][ct][reg];
        int code = (codeTile0 + wc*4 + ct)*16 + n;
        if (d < bd) { bd = d; bi = code; }
      }
      unsigned long long k = pack_key(bd, bi);
      unsigned long long v;
      v = __shfl_xor(k, 1); k = (v < k) ? v : k;
      v = __shfl_xor(k, 2); k = (v < k) ? v : k;
      v = __shfl_xor(k, 4); k = (v < k) ? v : k;
      v = __shfl_xor(k, 8); k = (v < k) ? v : k;
      if (n == 0) {
        int row = (rowTile0 + wr*8 + rt)*16 + q*4 + reg;
        atomicMin(&keys[row], k);
      }
    }
  }
}

// ================= fused gate + tail output (+ index unpack folded in) =================
__global__ __launch_bounds__(256)
void fuse_out(const float* __restrict__ src, const unsigned long long* __restrict__ keys,
              const float* __restrict__ gA, const float* __restrict__ uvec,
              const float* __restrict__ Mm, const float* __restrict__ tailcode,
              float* __restrict__ out, float* __restrict__ outIdx) {
  __shared__ float ss[32][257];
  __shared__ float s0s[32];
  __shared__ int ids[32];
  const int tid = threadIdx.x;
  const int rb = blockIdx.x * 32;
  const int b = rb >> 10;
  const int p0 = rb & 1023;
#pragma unroll
  for (int qq = 0; qq < 32; ++qq)
    ss[qq][tid] = src[(long)(p0 + qq) * (BSZ*HID) + b*HID + tid];
  if (tid < 32) {
    unsigned long long u = keys[rb + tid];
    int id = (int)(unsigned int)(u & 0xFFFFFFFFull);
    ids[tid] = id;
    outIdx[rb + tid] = (float)id;
  }
  __syncthreads();
  {
    const int wv = tid >> 6, lane = tid & 63;
    for (int qq = 0; qq < 8; ++qq) {
      int qp = wv*8 + qq;
      float a0 = 0.f, a1 = 0.f;
#pragma unroll
      for (int i = 0; i < 4; ++i) {
        float v = ss[qp][lane + 64*i];
        a0 += v * uvec[lane + 64*i];
        a1 += v * uvec[HID + lane + 64*i];
      }
#pragma unroll
      for (int off = 32; off; off >>= 1) { a0 += __shfl_down(a0, off); a1 += __shfl_down(a1, off); }
      if (lane == 0) {
        int id = ids[qp];
        float l0 = gA[id] + a0;
        float l1 = gA[NCODE + id] + a1;
        s0s[qp] = 1.0f / (1.0f + expf(l1 - l0));
      }
    }
  }
  __syncthreads();
  const int qg = tid >> 5, cg = tid & 31;
  const int q0 = qg * 4, c0 = cg * 8;
  float acc[4][8] = {};
  for (int cp = 0; cp < HID; ++cp) {
    float4 m0 = *(const float4*)(Mm + cp*HID + c0);
    float4 m1 = *(const float4*)(Mm + cp*HID + c0 + 4);
    float mm[8] = {m0.x,m0.y,m0.z,m0.w,m1.x,m1.y,m1.z,m1.w};
#pragma unroll
    for (int i = 0; i < 4; ++i) {
      float sv = ss[q0+i][cp];
#pragma unroll
      for (int j = 0; j < 8; ++j) acc[i][j] += sv * mm[j];
    }
  }
#pragma unroll
  for (int i = 0; i < 4; ++i) {
    int qp = q0 + i;
    int id = ids[qp];
    float s0 = s0s[qp], s1 = 1.0f - s0;
    const float* tc = tailcode + (long)id*HID + c0;
    float* op = out + (long)(p0+qp)*(BSZ*HID) + b*HID + c0;
    float4 o0, o1;
    o0.x = s0*tc[0] + s1*acc[i][0]; o0.y = s0*tc[1] + s1*acc[i][1];
    o0.z = s0*tc[2] + s1*acc[i][2]; o0.w = s0*tc[3] + s1*acc[i][3];
    o1.x = s0*tc[4] + s1*acc[i][4]; o1.y = s0*tc[5] + s1*acc[i][5];
    o1.z = s0*tc[6] + s1*acc[i][6]; o1.w = s0*tc[7] + s1*acc[i][7];
    *(float4*)(op) = o0; *(float4*)(op+4) = o1;
  }
}

// ================= launch =================
extern "C" void kernel_launch(void* const* d_in, const int* in_sizes, int n_in,
                              void* d_out, int out_size, void* d_ws, size_t ws_size,
                              hipStream_t stream) {
  const float* src    = (const float*)d_in[0];
  const float* cb     = (const float*)d_in[1];
  const float* w_head = (const float*)d_in[2];
  const float* w_tail = (const float*)d_in[3];
  const float* w_pos  = (const float*)d_in[4];
  const float* b_pos  = (const float*)d_in[5];
  const float* w_gate = (const float*)d_in[6];
  float* out = (float*)d_out;

  char* wsp = (char*)d_ws;
  size_t off = 0;
  auto alloc = [&](size_t bytes) {
    off = (off + 255) & ~(size_t)255;
    void* p = wsp + off; off += bytes; return p;
  };
  u16* xqh = (u16*)alloc((size_t)BSZ*TOKD*NVIS*2);  // 50.3 MB
  u16* xql = (u16*)alloc((size_t)BSZ*TOKD*NVIS*2);  // 50.3 MB
  u16* cbh = (u16*)alloc((size_t)NCODE*TOKD*2);
  u16* cbl = (u16*)alloc((size_t)NCODE*TOKD*2);
  u16* whh = (u16*)alloc((size_t)TOKD*HID*2);
  u16* whl = (u16*)alloc((size_t)TOKD*HID*2);
  float* cbn      = (float*)alloc((size_t)NCODE*4);
  float* Gt       = (float*)alloc((size_t)TOKD*HID*4);
  float* g2       = (float*)alloc((size_t)2*TOKD*4);
  float* ct0      = (float*)alloc((size_t)HID*4);
  float* cg       = (float*)alloc((size_t)2*4);
  float* tailcode = (float*)alloc((size_t)NCODE*HID*4);
  float* gA       = (float*)alloc((size_t)2*NCODE*4);
  float* Mm       = (float*)alloc((size_t)HID*HID*4);
  float* uvec     = (float*)alloc((size_t)2*HID*4);
  unsigned long long* keys = (unsigned long long*)alloc((size_t)NPIX*8);
  (void)ws_size; (void)in_sizes; (void)n_in; (void)out_size;

  prep1<<<8455, 256, 0, stream>>>(cb, w_head, w_tail, w_pos, w_gate, b_pos,
                                  cbh, cbl, whh, whl, cbn, Mm, uvec, Gt, g2, ct0, cg);
  retile<<<NCODE/16, 256, 0, stream>>>(cbh, cbl);          // codebook -> frag-tiled
  prep2<<<NCODE/8, 256, 0, stream>>>(cb, Gt, ct0, g2, cg, tailcode, gA);

  head_mfma<<<dim3(TOKD/128, NVIS/128, BSZ), 256, 0, stream>>>(whh, whl, src, xqh, xql);
  retile<<<NPIX/16, 256, 0, stream>>>(xqh, xql);           // xq -> frag-tiled (in place)

  hipMemsetAsync(keys, 0xFF, (size_t)NPIX*8, stream);
  vq_mfma<<<1024, 512, 0, stream>>>(xqh, xql, cbh, cbl, cbn, keys);

  fuse_out<<<NPIX/32, 256, 0, stream>>>(src, keys, gA, uvec, Mm, tailcode,
                                        out, out + (size_t)NVIS*BSZ*HID);
}

// Round 3
// 707.314 us; speedup vs baseline: 1.0042x; 1.0042x over previous
//
#include <hip/hip_runtime.h>
#include <cstdint>

#define BSZ 32
#define NVIS 1024
#define HID 256
#define TOKD 768
#define NCODE 2048
#define NPIX 32768

typedef unsigned short u16;
typedef _Float16 half8 __attribute__((ext_vector_type(8)));
typedef unsigned short ushort8 __attribute__((ext_vector_type(8)));
using f32x4 = __attribute__((ext_vector_type(4))) float;

#define AS1 __attribute__((address_space(1)))
#define AS3 __attribute__((address_space(3)))

__device__ __forceinline__ f32x4 mfmaF16(half8 a, half8 b, f32x4 c) {
  return __builtin_amdgcn_mfma_f32_16x16x32_f16(a, b, c, 0, 0, 0);
}

__device__ __forceinline__ unsigned long long pack_key(float d, int idx) {
  unsigned int b = __float_as_uint(d);
  b = (b & 0x80000000u) ? ~b : (b | 0x80000000u);  // monotonic float->uint
  return ((unsigned long long)b << 32) | (unsigned int)idx;
}

__device__ __forceinline__ void split16(float v, u16& h, u16& l) {
  union { _Float16 f; u16 u; } a, b;
  a.f = (_Float16)v;
  float hf = (float)a.f;
  b.f = (_Float16)(v - hf);
  h = a.u; l = b.u;
}

// ================= prep1: all weights-only precompute, one launch =================
__global__ __launch_bounds__(256)
void prep1(const float* __restrict__ cb, const float* __restrict__ wh,
           const float* __restrict__ wt, const float* __restrict__ wp,
           const float* __restrict__ wg, const float* __restrict__ bp,
           u16* __restrict__ cbh, u16* __restrict__ cbl,
           u16* __restrict__ whh, u16* __restrict__ whl,
           float* __restrict__ cbn, float* __restrict__ Mm, float* __restrict__ uv,
           float* __restrict__ Gt, float* __restrict__ g2,
           float* __restrict__ ct0, float* __restrict__ cg) {
  const int bid = blockIdx.x, tid = threadIdx.x;
  if (bid < 6144) {                       // split cb
    int i = bid*256 + tid;
    u16 h, l; split16(cb[i], h, l);
    cbh[i] = h; cbl[i] = l;
  } else if (bid < 6912) {                // split w_head
    int i = (bid - 6144)*256 + tid;
    u16 h, l; split16(wh[i], h, l);
    whh[i] = h; whl[i] = l;
  } else if (bid < 7424) {                // code norms
    int n = (bid - 6912)*4 + (tid >> 6);
    int lane = tid & 63;
    float a = 0.f;
#pragma unroll
    for (int i = 0; i < 12; ++i) { float v = cb[(long)n*TOKD + lane + 64*i]; a += v*v; }
#pragma unroll
    for (int off = 32; off; off >>= 1) a += __shfl_down(a, off);
    if (lane == 0) cbn[n] = a;
  } else if (bid < 7680) {                // make_M
    int c2 = bid - 7424, c1 = tid;
    float acc = 0.f;
    for (int t = 0; t < TOKD; ++t) acc += wh[t*HID + c1] * wt[(long)c2*TOKD + t];
    Mm[c1*HID + c2] = acc;
  } else if (bid < 7682) {                // make_u
    int o = bid - 7680, c1 = tid;
    float acc = 0.f;
    for (int t = 0; t < TOKD; ++t) acc += wh[t*HID + c1] * wg[o*(2*TOKD) + TOKD + t];
    uv[o*HID + c1] = acc;
  } else if (bid < 8450) {                // make_Gt
    int rbid = bid - 7682;
    int c = rbid & 255, part = rbid >> 8;
    int tp = part*256 + tid;
    float acc = 0.f;
    for (int t = 0; t < TOKD; ++t) acc += wt[(long)c*TOKD + t] * wp[(long)t*TOKD + tp];
    Gt[(long)tp*HID + c] = acc;
  } else if (bid < 8453) {                // g2
    int tp = (bid - 8450)*256 + tid;
    float a0 = 0.f, a1 = 0.f;
    for (int t = 0; t < TOKD; ++t) {
      float wv = wp[(long)t*TOKD + tp];
      a0 += wv * wg[t];
      a1 += wv * wg[2*TOKD + t];
    }
    g2[tp] = a0; g2[TOKD + tp] = a1;
  } else if (bid < 8454) {                // ct0
    int c = tid;
    float a = 0.f;
    for (int t = 0; t < TOKD; ++t) a += bp[t] * wt[(long)c*TOKD + t];
    ct0[c] = a;
  } else {                                // cg
    int o = tid >> 6, lane = tid & 63;
    if (o < 2) {
      float a = 0.f;
      for (int t = lane; t < TOKD; t += 64) a += bp[t] * wg[o*(2*TOKD) + t];
#pragma unroll
      for (int off = 32; off; off >>= 1) a += __shfl_down(a, off);
      if (lane == 0) cg[o] = a;
    }
  }
}

// ================= prep2: tailcode + gA from shared cb tile =================
__global__ __launch_bounds__(256)
void prep2(const float* __restrict__ cb, const float* __restrict__ Gt,
           const float* __restrict__ ct0, const float* __restrict__ g2,
           const float* __restrict__ cg, float* __restrict__ tc,
           float* __restrict__ gA) {
  __shared__ float cbs[8][TOKD];
  const int n0 = blockIdx.x * 8, tid = threadIdx.x;
  for (int i = tid; i < 8*TOKD; i += 256) cbs[i / TOKD][i % TOKD] = cb[(long)n0*TOKD + i];
  __syncthreads();
  float acc[8] = {};
  for (int t = 0; t < TOKD; ++t) {
    float gv = Gt[(long)t*HID + tid];
#pragma unroll
    for (int i = 0; i < 8; ++i) acc[i] += cbs[i][t] * gv;
  }
  float c0v = ct0[tid];
#pragma unroll
  for (int i = 0; i < 8; ++i) tc[(long)(n0+i)*HID + tid] = acc[i] + c0v;
  {
    int i = tid >> 5, l32 = tid & 31;
    float a0 = 0.f, a1 = 0.f;
    for (int t = l32; t < TOKD; t += 32) {
      float cv = cbs[i][t];
      a0 += cv * g2[t];
      a1 += cv * g2[TOKD + t];
    }
#pragma unroll
    for (int off = 16; off; off >>= 1) { a0 += __shfl_down(a0, off); a1 += __shfl_down(a1, off); }
    if (l32 == 0) { gA[n0+i] = a0 + cg[0]; gA[NCODE + n0+i] = a1 + cg[1]; }
  }
}

// ================= head GEMM (round-4 verified, row-major coalesced stores) =================
__global__ __launch_bounds__(256)
void head_mfma(const u16* __restrict__ whh, const u16* __restrict__ whl,
               const float* __restrict__ src,
               u16* __restrict__ xqh, u16* __restrict__ xql) {
  __shared__ u16 SM[32768] __attribute__((aligned(16)));   // 64 KB
  u16* Ah = SM;            // [2][4096]
  u16* Al = SM + 8192;
  u16* Bh = SM + 16384;
  u16* Bl = SM + 24576;
  const int tid = threadIdx.x, lane = tid & 63, w = tid >> 6;
  const int n = lane & 15, q = lane >> 4;
  const int rh = w & 1, ch = w >> 1;
  const int obase = blockIdx.x * 128, pbase = blockIdx.y * 128, b = blockIdx.z;

  auto stageA = [&](int kc, int buf) {
#pragma unroll
    for (int is = 0; is < 2; ++is) {
      int c = is*256 + tid;
      int t = c >> 6, qq = (c >> 4) & 3, nn = c & 15;
      long off = (long)(obase + t*16 + nn)*HID + kc*32 + qq*8;
      __builtin_amdgcn_global_load_lds((AS1 void*)(whh + off),
          (AS3 void*)&Ah[buf*4096 + c*8], 16, 0, 0);
      __builtin_amdgcn_global_load_lds((AS1 void*)(whl + off),
          (AS3 void*)&Al[buf*4096 + c*8], 16, 0, 0);
    }
  };
  auto stageB = [&](int kc, int buf) {
#pragma unroll
    for (int is = 0; is < 2; ++is) {
      int c = is*256 + tid;
      int t = c >> 6, qq = (c >> 4) & 3, nn = c & 15;
      const float* gp = src + ((long)(pbase + t*16 + nn)*BSZ + b)*HID + kc*32 + qq*8;
      float4 v0 = *(const float4*)gp;
      float4 v1 = *(const float4*)(gp + 4);
      float vv[8] = {v0.x, v0.y, v0.z, v0.w, v1.x, v1.y, v1.z, v1.w};
      ushort8 hv, lv;
#pragma unroll
      for (int j = 0; j < 8; ++j) { u16 hs, ls; split16(vv[j], hs, ls); hv[j] = hs; lv[j] = ls; }
      *(ushort8*)&Bh[buf*4096 + c*8] = hv;
      *(ushort8*)&Bl[buf*4096 + c*8] = lv;
    }
  };

  f32x4 acc[4][4];
#pragma unroll
  for (int i = 0; i < 4; ++i)
#pragma unroll
    for (int j = 0; j < 4; ++j) acc[i][j] = (f32x4){0.f, 0.f, 0.f, 0.f};

  stageA(0, 0); stageB(0, 0);
  __syncthreads();

  for (int kt = 0; kt < HID/32; ++kt) {
    const int buf = kt & 1;
    if (kt + 1 < HID/32) { stageA(kt + 1, buf ^ 1); stageB(kt + 1, buf ^ 1); }
    half8 af[4][2], bf[4][2];
#pragma unroll
    for (int rt = 0; rt < 4; ++rt) {
      int idx = buf*4096 + ((rh*4 + rt)*64 + q*16 + n)*8;
      af[rt][0] = *(const half8*)&Ah[idx];
      af[rt][1] = *(const half8*)&Al[idx];
    }
#pragma unroll
    for (int ct = 0; ct < 4; ++ct) {
      int idx = buf*4096 + ((ch*4 + ct)*64 + q*16 + n)*8;
      bf[ct][0] = *(const half8*)&Bh[idx];
      bf[ct][1] = *(const half8*)&Bl[idx];
    }
#pragma unroll
    for (int rt = 0; rt < 4; ++rt)
#pragma unroll
      for (int ct = 0; ct < 4; ++ct) {
        acc[rt][ct] = mfmaF16(af[rt][0], bf[ct][0], acc[rt][ct]);
        acc[rt][ct] = mfmaF16(af[rt][0], bf[ct][1], acc[rt][ct]);
        acc[rt][ct] = mfmaF16(af[rt][1], bf[ct][0], acc[rt][ct]);
      }
    __syncthreads();
  }

#pragma unroll
  for (int pass = 0; pass < 2; ++pass) {
    u16* dst = pass ? xql : xqh;
#pragma unroll
    for (int rt = 0; rt < 4; ++rt)
#pragma unroll
      for (int ct = 0; ct < 4; ++ct)
#pragma unroll
        for (int reg = 0; reg < 4; ++reg) {
          u16 hs, ls; split16(acc[rt][ct][reg], hs, ls);
          int ol = rh*64 + rt*16 + q*4 + reg;
          int pl = ch*64 + ct*16 + n;
          SM[ol*136 + pl] = pass ? ls : hs;
        }
    __syncthreads();
#pragma unroll
    for (int s = 0; s < 8; ++s) {
      int cc = tid*8 + s;
      int o = cc >> 4, p8 = cc & 15;
      ushort8 v = *(const ushort8*)&SM[o*136 + p8*8];
      *(ushort8*)(dst + ((long)b*TOKD + obase + o)*NVIS + pbase + p8*8) = v;
    }
    __syncthreads();
  }
}

// ================= retile: in-place row-major -> MFMA-fragment-tiled =================
__global__ __launch_bounds__(256)
void retile(u16* __restrict__ bufH, u16* __restrict__ bufL) {
  __shared__ u16 T[96*136] __attribute__((aligned(16)));
  const long tile = blockIdx.x;
  const int tid = threadIdx.x;
#pragma unroll
  for (int pass = 0; pass < 2; ++pass) {
    u16* buf = pass ? bufL : bufH;
    if (pass) __syncthreads();
#pragma unroll
    for (int i = 0; i < 6; ++i) {
      int g = i*256 + tid;
      int row = g / 96, c16 = g % 96;
      ushort8 v = *(const ushort8*)(buf + tile*12288 + row*768 + c16*8);
      *(ushort8*)&T[c16*136 + row*8] = v;
    }
    __syncthreads();
#pragma unroll
    for (int i = 0; i < 6; ++i) {
      int g = i*256 + tid;
      int kc = g >> 6, lp = g & 63;
      int q = lp >> 4, n = lp & 15;
      ushort8 v = *(const ushort8*)&T[(kc*4 + q)*136 + n*8];
      *(ushort8*)(buf + tile*12288 + (long)kc*512 + lp*8) = v;
    }
  }
}

// ================= VQ: 256x128-tile, 2-deep LDS (48KB) -> TWO blocks/CU ===================
// The round-1/2 kernels ran 1 block/CU (128KB LDS): all 8 waves in one barrier domain ->
// per-iter [ds_read burst ~900cy][MFMA burst ~1242cy] strictly serial (measured 2583cy/iter,
// MfmaUtil 45%). Fix: 256-thr blocks, 48KB LDS -> 2 independent blocks/CU whose phases slide
// against each other (m114 co-schedule): block A's MFMA overlaps block B's LDS traffic.
// Block tile 256 rows x 128 codes, 4 waves (2x2), wave tile 128x64 (8x4 frags, 32 MFMA/iter).
// Grid 2048: xcd=bid&7 owns a 4096-row band (A filled once/XCD); codeBlk=slot&15 fastest.
// Schedule per iter (round-1-proven, compiler-scheduled lgkmcnt): stage(ht+1) -> plain-C++
// frag reads (compiler interleaves ds_read/MFMA with fine-grained lgkmcnt) -> 32 MFMA ->
// __syncthreads() (drains vmcnt for buf^1 publish + protects buf reuse).
__global__ __launch_bounds__(256, 2)
void vq_mfma(const u16* __restrict__ xqh, const u16* __restrict__ xql,
             const u16* __restrict__ cbh, const u16* __restrict__ cbl,
             const float* __restrict__ cbn, unsigned long long* __restrict__ keys) {
  __shared__ u16 SM[24576] __attribute__((aligned(16)));   // 48 KB: A[2][8192] | B[2][4096]
  const int bid = blockIdx.x;
  const int xcd = bid & 7, slot = bid >> 3;          // slot 0..255
  const int rowBlk = xcd * 16 + (slot >> 4);         // 0..127 (16 per XCD)
  const int codeBlk = slot & 15;                     // 0..15, fastest-cycling within XCD
  const int rowTile0 = rowBlk * 16;                  // of 2048 row-tiles (16 rows each)
  const int codeTile0 = codeBlk * 8;                 // of 128 code-tiles
  const int tid = threadIdx.x, lane = tid & 63, w = tid >> 6;   // w in 0..3
  const int n = lane & 15, q = lane >> 4;
  const int wr = w >> 1, wc = w & 1;

  // staging: wave w stages A row-tiles {4w..4w+3} and B code-tiles {2w,2w+1}
  const size_t aOff = (size_t)(rowTile0 + 4*w) * 12288 + lane*8;
  const size_t bOff = (size_t)(codeTile0 + 2*w) * 12288 + lane*8;
  const int aChunk = (4*w)*512 + lane*8;
  const int bChunk = (2*w)*512 + lane*8;

  auto STAGE = [&](int ht, int buf) {
    const int seg = (ht >= 48) ? 2 : ((ht >= 24) ? 1 : 0);
    const int kk = ht - seg * 24;
    const u16* pa = ((seg == 1) ? xql : xqh) + aOff + kk*512;
    const u16* pb = ((seg == 2) ? cbl : cbh) + bOff + kk*512;
    u16* la = &SM[buf*8192 + aChunk];
    u16* lb = &SM[16384 + buf*4096 + bChunk];
    __builtin_amdgcn_global_load_lds((AS1 void*)pa,             (AS3 void*)la,          16, 0, 0);
    __builtin_amdgcn_global_load_lds((AS1 void*)(pa + 12288),   (AS3 void*)(la + 512),  16, 0, 0);
    __builtin_amdgcn_global_load_lds((AS1 void*)(pa + 2*12288), (AS3 void*)(la + 1024), 16, 0, 0);
    __builtin_amdgcn_global_load_lds((AS1 void*)(pa + 3*12288), (AS3 void*)(la + 1536), 16, 0, 0);
    __builtin_amdgcn_global_load_lds((AS1 void*)pb,             (AS3 void*)lb,          16, 0, 0);
    __builtin_amdgcn_global_load_lds((AS1 void*)(pb + 12288),   (AS3 void*)(lb + 512),  16, 0, 0);
  };

  f32x4 acc[8][4];
#pragma unroll
  for (int a = 0; a < 8; ++a)
#pragma unroll
    for (int b2 = 0; b2 < 4; ++b2) acc[a][b2] = (f32x4){0.f, 0.f, 0.f, 0.f};

  STAGE(0, 0);
  __syncthreads();                                   // drains vmcnt -> buf0 published

#pragma unroll 1
  for (int ht = 0; ht < 72; ++ht) {
    const int buf = ht & 1;
    if (ht < 71) STAGE(ht + 1, buf ^ 1);
    half8 Af[8], Bf[4];
    const int ab = buf*8192 + (wr*8)*512 + lane*8;
    const int bb = 16384 + buf*4096 + (wc*4)*512 + lane*8;
#pragma unroll
    for (int rt = 0; rt < 8; ++rt) Af[rt] = *(const half8*)&SM[ab + rt*512];
#pragma unroll
    for (int ct = 0; ct < 4; ++ct) Bf[ct] = *(const half8*)&SM[bb + ct*512];
    __builtin_amdgcn_s_setprio(1);
#pragma unroll
    for (int rt = 0; rt < 8; ++rt)
#pragma unroll
      for (int ct = 0; ct < 4; ++ct)
        acc[rt][ct] = mfmaF16(Af[rt], Bf[ct], acc[rt][ct]);
    __builtin_amdgcn_s_setprio(0);
    __syncthreads();   // drains vmcnt(0)+lgkmcnt(0): buf^1 fully staged, buf reads done
  }

  // argmin epilogue: lane holds (row = rt*16 + q*4 + reg, code = ct*16 + n) in wave tiles
  float cbv[4];
#pragma unroll
  for (int ct = 0; ct < 4; ++ct) cbv[ct] = cbn[(codeTile0 + wc*4 + ct)*16 + n];
#pragma unroll
  for (int rt = 0; rt < 8; ++rt) {
#pragma unroll
    for (int reg = 0; reg < 4; ++reg) {
      float bd = 3.4e38f; int bi = 0;
#pragma unroll
      for (int ct = 0; ct < 4; ++ct) {
        float d = cbv[ct] - 2.0f * acc[rt][ct][reg];
        int code = (codeTile0 + wc*4 + ct)*16 + n;
        if (d < bd) { bd = d; bi = code; }
      }
      unsigned long long k = pack_key(bd, bi);
      unsigned long long v;
      v = __shfl_xor(k, 1); k = (v < k) ? v : k;
      v = __shfl_xor(k, 2); k = (v < k) ? v : k;
      v = __shfl_xor(k, 4); k = (v < k) ? v : k;
      v = __shfl_xor(k, 8); k = (v < k) ? v : k;
      if (n == 0) {
        int row = (rowTile0 + wr*8 + rt)*16 + q*4 + reg;
        atomicMin(&keys[row], k);
      }
    }
  }
}

// ================= fused gate + tail output (+ index unpack folded in) =================
__global__ __launch_bounds__(256)
void fuse_out(const float* __restrict__ src, const unsigned long long* __restrict__ keys,
              const float* __restrict__ gA, const float* __restrict__ uvec,
              const float* __restrict__ Mm, const float* __restrict__ tailcode,
              float* __restrict__ out, float* __restrict__ outIdx) {
  __shared__ float ss[32][257];
  __shared__ float s0s[32];
  __shared__ int ids[32];
  const int tid = threadIdx.x;
  const int rb = blockIdx.x * 32;
  const int b = rb >> 10;
  const int p0 = rb & 1023;
#pragma unroll
  for (int qq = 0; qq < 32; ++qq)
    ss[qq][tid] = src[(long)(p0 + qq) * (BSZ*HID) + b*HID + tid];
  if (tid < 32) {
    unsigned long long u = keys[rb + tid];
    int id = (int)(unsigned int)(u & 0xFFFFFFFFull);
    ids[tid] = id;
    outIdx[rb + tid] = (float)id;
  }
  __syncthreads();
  {
    const int wv = tid >> 6, lane = tid & 63;
    for (int qq = 0; qq < 8; ++qq) {
      int qp = wv*8 + qq;
      float a0 = 0.f, a1 = 0.f;
#pragma unroll
      for (int i = 0; i < 4; ++i) {
        float v = ss[qp][lane + 64*i];
        a0 += v * uvec[lane + 64*i];
        a1 += v * uvec[HID + lane + 64*i];
      }
#pragma unroll
      for (int off = 32; off; off >>= 1) { a0 += __shfl_down(a0, off); a1 += __shfl_down(a1, off); }
      if (lane == 0) {
        int id = ids[qp];
        float l0 = gA[id] + a0;
        float l1 = gA[NCODE + id] + a1;
        s0s[qp] = 1.0f / (1.0f + expf(l1 - l0));
      }
    }
  }
  __syncthreads();
  const int qg = tid >> 5, cg = tid & 31;
  const int q0 = qg * 4, c0 = cg * 8;
  float acc[4][8] = {};
  for (int cp = 0; cp < HID; ++cp) {
    float4 m0 = *(const float4*)(Mm + cp*HID + c0);
    float4 m1 = *(const float4*)(Mm + cp*HID + c0 + 4);
    float mm[8] = {m0.x,m0.y,m0.z,m0.w,m1.x,m1.y,m1.z,m1.w};
#pragma unroll
    for (int i = 0; i < 4; ++i) {
      float sv = ss[q0+i][cp];
#pragma unroll
      for (int j = 0; j < 8; ++j) acc[i][j] += sv * mm[j];
    }
  }
#pragma unroll
  for (int i = 0; i < 4; ++i) {
    int qp = q0 + i;
    int id = ids[qp];
    float s0 = s0s[qp], s1 = 1.0f - s0;
    const float* tc = tailcode + (long)id*HID + c0;
    float* op = out + (long)(p0+qp)*(BSZ*HID) + b*HID + c0;
    float4 o0, o1;
    o0.x = s0*tc[0] + s1*acc[i][0]; o0.y = s0*tc[1] + s1*acc[i][1];
    o0.z = s0*tc[2] + s1*acc[i][2]; o0.w = s0*tc[3] + s1*acc[i][3];
    o1.x = s0*tc[4] + s1*acc[i][4]; o1.y = s0*tc[5] + s1*acc[i][5];
    o1.z = s0*tc[6] + s1*acc[i][6]; o1.w = s0*tc[7] + s1*acc[i][7];
    *(float4*)(op) = o0; *(float4*)(op+4) = o1;
  }
}

// ================= launch =================
extern "C" void kernel_launch(void* const* d_in, const int* in_sizes, int n_in,
                              void* d_out, int out_size, void* d_ws, size_t ws_size,
                              hipStream_t stream) {
  const float* src    = (const float*)d_in[0];
  const float* cb     = (const float*)d_in[1];
  const float* w_head = (const float*)d_in[2];
  const float* w_tail = (const float*)d_in[3];
  const float* w_pos  = (const float*)d_in[4];
  const float* b_pos  = (const float*)d_in[5];
  const float* w_gate = (const float*)d_in[6];
  float* out = (float*)d_out;

  char* wsp = (char*)d_ws;
  size_t off = 0;
  auto alloc = [&](size_t bytes) {
    off = (off + 255) & ~(size_t)255;
    void* p = wsp + off; off += bytes; return p;
  };
  u16* xqh = (u16*)alloc((size_t)BSZ*TOKD*NVIS*2);  // 50.3 MB
  u16* xql = (u16*)alloc((size_t)BSZ*TOKD*NVIS*2);  // 50.3 MB
  u16* cbh = (u16*)alloc((size_t)NCODE*TOKD*2);
  u16* cbl = (u16*)alloc((size_t)NCODE*TOKD*2);
  u16* whh = (u16*)alloc((size_t)TOKD*HID*2);
  u16* whl = (u16*)alloc((size_t)TOKD*HID*2);
  float* cbn      = (float*)alloc((size_t)NCODE*4);
  float* Gt       = (float*)alloc((size_t)TOKD*HID*4);
  float* g2       = (float*)alloc((size_t)2*TOKD*4);
  float* ct0      = (float*)alloc((size_t)HID*4);
  float* cg       = (float*)alloc((size_t)2*4);
  float* tailcode = (float*)alloc((size_t)NCODE*HID*4);
  float* gA       = (float*)alloc((size_t)2*NCODE*4);
  float* Mm       = (float*)alloc((size_t)HID*HID*4);
  float* uvec     = (float*)alloc((size_t)2*HID*4);
  unsigned long long* keys = (unsigned long long*)alloc((size_t)NPIX*8);
  (void)ws_size; (void)in_sizes; (void)n_in; (void)out_size;

  prep1<<<8455, 256, 0, stream>>>(cb, w_head, w_tail, w_pos, w_gate, b_pos,
                                  cbh, cbl, whh, whl, cbn, Mm, uvec, Gt, g2, ct0, cg);
  retile<<<NCODE/16, 256, 0, stream>>>(cbh, cbl);          // codebook -> frag-tiled
  prep2<<<NCODE/8, 256, 0, stream>>>(cb, Gt, ct0, g2, cg, tailcode, gA);

  head_mfma<<<dim3(TOKD/128, NVIS/128, BSZ), 256, 0, stream>>>(whh, whl, src, xqh, xql);
  retile<<<NPIX/16, 256, 0, stream>>>(xqh, xql);           // xq -> frag-tiled (in place)

  hipMemsetAsync(keys, 0xFF, (size_t)NPIX*8, stream);
  vq_mfma<<<2048, 256, 0, stream>>>(xqh, xql, cbh, cbl, cbn, keys);

  fuse_out<<<NPIX/32, 256, 0, stream>>>(src, keys, gA, uvec, Mm, tailcode,
                                        out, out + (size_t)NVIS*BSZ*HID);
}

// Round 5
// 657.392 us; speedup vs baseline: 1.0805x; 1.0759x over previous
//
#include <hip/hip_runtime.h>
#include <cstdint>

#define BSZ 32
#define NVIS 1024
#define HID 256
#define TOKD 768
#define NCODE 2048
#define NPIX 32768

typedef unsigned short u16;
typedef _Float16 half8 __attribute__((ext_vector_type(8)));
typedef unsigned short ushort8 __attribute__((ext_vector_type(8)));
using f32x4 = __attribute__((ext_vector_type(4))) float;

#define AS1 __attribute__((address_space(1)))
#define AS3 __attribute__((address_space(3)))

__device__ __forceinline__ f32x4 mfmaF16(half8 a, half8 b, f32x4 c) {
  return __builtin_amdgcn_mfma_f32_16x16x32_f16(a, b, c, 0, 0, 0);
}

__device__ __forceinline__ unsigned long long pack_key(float d, int idx) {
  unsigned int b = __float_as_uint(d);
  b = (b & 0x80000000u) ? ~b : (b | 0x80000000u);  // monotonic float->uint
  return ((unsigned long long)b << 32) | (unsigned int)idx;
}

__device__ __forceinline__ void split16(float v, u16& h, u16& l) {
  union { _Float16 f; u16 u; } a, b;
  a.f = (_Float16)v;
  float hf = (float)a.f;
  b.f = (_Float16)(v - hf);
  h = a.u; l = b.u;
}

// ================= prep1: all weights-only precompute, one launch =================
__global__ __launch_bounds__(256)
void prep1(const float* __restrict__ cb, const float* __restrict__ wh,
           const float* __restrict__ wt, const float* __restrict__ wp,
           const float* __restrict__ wg, const float* __restrict__ bp,
           u16* __restrict__ cbh, u16* __restrict__ cbl,
           u16* __restrict__ whh, u16* __restrict__ whl,
           float* __restrict__ cbn, float* __restrict__ Mm, float* __restrict__ uv,
           float* __restrict__ Gt, float* __restrict__ g2,
           float* __restrict__ ct0, float* __restrict__ cg) {
  const int bid = blockIdx.x, tid = threadIdx.x;
  if (bid < 6144) {                       // split cb
    int i = bid*256 + tid;
    u16 h, l; split16(cb[i], h, l);
    cbh[i] = h; cbl[i] = l;
  } else if (bid < 6912) {                // split w_head
    int i = (bid - 6144)*256 + tid;
    u16 h, l; split16(wh[i], h, l);
    whh[i] = h; whl[i] = l;
  } else if (bid < 7424) {                // code norms
    int n = (bid - 6912)*4 + (tid >> 6);
    int lane = tid & 63;
    float a = 0.f;
#pragma unroll
    for (int i = 0; i < 12; ++i) { float v = cb[(long)n*TOKD + lane + 64*i]; a += v*v; }
#pragma unroll
    for (int off = 32; off; off >>= 1) a += __shfl_down(a, off);
    if (lane == 0) cbn[n] = a;
  } else if (bid < 7680) {                // make_M
    int c2 = bid - 7424, c1 = tid;
    float acc = 0.f;
    for (int t = 0; t < TOKD; ++t) acc += wh[t*HID + c1] * wt[(long)c2*TOKD + t];
    Mm[c1*HID + c2] = acc;
  } else if (bid < 7682) {                // make_u
    int o = bid - 7680, c1 = tid;
    float acc = 0.f;
    for (int t = 0; t < TOKD; ++t) acc += wh[t*HID + c1] * wg[o*(2*TOKD) + TOKD + t];
    uv[o*HID + c1] = acc;
  } else if (bid < 8450) {                // make_Gt
    int rbid = bid - 7682;
    int c = rbid & 255, part = rbid >> 8;
    int tp = part*256 + tid;
    float acc = 0.f;
    for (int t = 0; t < TOKD; ++t) acc += wt[(long)c*TOKD + t] * wp[(long)t*TOKD + tp];
    Gt[(long)tp*HID + c] = acc;
  } else if (bid < 8453) {                // g2
    int tp = (bid - 8450)*256 + tid;
    float a0 = 0.f, a1 = 0.f;
    for (int t = 0; t < TOKD; ++t) {
      float wv = wp[(long)t*TOKD + tp];
      a0 += wv * wg[t];
      a1 += wv * wg[2*TOKD + t];
    }
    g2[tp] = a0; g2[TOKD + tp] = a1;
  } else if (bid < 8454) {                // ct0
    int c = tid;
    float a = 0.f;
    for (int t = 0; t < TOKD; ++t) a += bp[t] * wt[(long)c*TOKD + t];
    ct0[c] = a;
  } else {                                // cg
    int o = tid >> 6, lane = tid & 63;
    if (o < 2) {
      float a = 0.f;
      for (int t = lane; t < TOKD; t += 64) a += bp[t] * wg[o*(2*TOKD) + t];
#pragma unroll
      for (int off = 32; off; off >>= 1) a += __shfl_down(a, off);
      if (lane == 0) cg[o] = a;
    }
  }
}

// ================= prep2: tailcode + gA from shared cb tile =================
__global__ __launch_bounds__(256)
void prep2(const float* __restrict__ cb, const float* __restrict__ Gt,
           const float* __restrict__ ct0, const float* __restrict__ g2,
           const float* __restrict__ cg, float* __restrict__ tc,
           float* __restrict__ gA) {
  __shared__ float cbs[8][TOKD];
  const int n0 = blockIdx.x * 8, tid = threadIdx.x;
  for (int i = tid; i < 8*TOKD; i += 256) cbs[i / TOKD][i % TOKD] = cb[(long)n0*TOKD + i];
  __syncthreads();
  float acc[8] = {};
  for (int t = 0; t < TOKD; ++t) {
    float gv = Gt[(long)t*HID + tid];
#pragma unroll
    for (int i = 0; i < 8; ++i) acc[i] += cbs[i][t] * gv;
  }
  float c0v = ct0[tid];
#pragma unroll
  for (int i = 0; i < 8; ++i) tc[(long)(n0+i)*HID + tid] = acc[i] + c0v;
  {
    int i = tid >> 5, l32 = tid & 31;
    float a0 = 0.f, a1 = 0.f;
    for (int t = l32; t < TOKD; t += 32) {
      float cv = cbs[i][t];
      a0 += cv * g2[t];
      a1 += cv * g2[TOKD + t];
    }
#pragma unroll
    for (int off = 16; off; off >>= 1) { a0 += __shfl_down(a0, off); a1 += __shfl_down(a1, off); }
    if (l32 == 0) { gA[n0+i] = a0 + cg[0]; gA[NCODE + n0+i] = a1 + cg[1]; }
  }
}

// ================= head GEMM (round-4 verified, row-major coalesced stores) =================
__global__ __launch_bounds__(256)
void head_mfma(const u16* __restrict__ whh, const u16* __restrict__ whl,
               const float* __restrict__ src,
               u16* __restrict__ xqh, u16* __restrict__ xql) {
  __shared__ u16 SM[32768] __attribute__((aligned(16)));   // 64 KB
  u16* Ah = SM;            // [2][4096]
  u16* Al = SM + 8192;
  u16* Bh = SM + 16384;
  u16* Bl = SM + 24576;
  const int tid = threadIdx.x, lane = tid & 63, w = tid >> 6;
  const int n = lane & 15, q = lane >> 4;
  const int rh = w & 1, ch = w >> 1;
  const int obase = blockIdx.x * 128, pbase = blockIdx.y * 128, b = blockIdx.z;

  auto stageA = [&](int kc, int buf) {
#pragma unroll
    for (int is = 0; is < 2; ++is) {
      int c = is*256 + tid;
      int t = c >> 6, qq = (c >> 4) & 3, nn = c & 15;
      long off = (long)(obase + t*16 + nn)*HID + kc*32 + qq*8;
      __builtin_amdgcn_global_load_lds((AS1 void*)(whh + off),
          (AS3 void*)&Ah[buf*4096 + c*8], 16, 0, 0);
      __builtin_amdgcn_global_load_lds((AS1 void*)(whl + off),
          (AS3 void*)&Al[buf*4096 + c*8], 16, 0, 0);
    }
  };
  auto stageB = [&](int kc, int buf) {
#pragma unroll
    for (int is = 0; is < 2; ++is) {
      int c = is*256 + tid;
      int t = c >> 6, qq = (c >> 4) & 3, nn = c & 15;
      const float* gp = src + ((long)(pbase + t*16 + nn)*BSZ + b)*HID + kc*32 + qq*8;
      float4 v0 = *(const float4*)gp;
      float4 v1 = *(const float4*)(gp + 4);
      float vv[8] = {v0.x, v0.y, v0.z, v0.w, v1.x, v1.y, v1.z, v1.w};
      ushort8 hv, lv;
#pragma unroll
      for (int j = 0; j < 8; ++j) { u16 hs, ls; split16(vv[j], hs, ls); hv[j] = hs; lv[j] = ls; }
      *(ushort8*)&Bh[buf*4096 + c*8] = hv;
      *(ushort8*)&Bl[buf*4096 + c*8] = lv;
    }
  };

  f32x4 acc[4][4];
#pragma unroll
  for (int i = 0; i < 4; ++i)
#pragma unroll
    for (int j = 0; j < 4; ++j) acc[i][j] = (f32x4){0.f, 0.f, 0.f, 0.f};

  stageA(0, 0); stageB(0, 0);
  __syncthreads();

  for (int kt = 0; kt < HID/32; ++kt) {
    const int buf = kt & 1;
    if (kt + 1 < HID/32) { stageA(kt + 1, buf ^ 1); stageB(kt + 1, buf ^ 1); }
    half8 af[4][2], bf[4][2];
#pragma unroll
    for (int rt = 0; rt < 4; ++rt) {
      int idx = buf*4096 + ((rh*4 + rt)*64 + q*16 + n)*8;
      af[rt][0] = *(const half8*)&Ah[idx];
      af[rt][1] = *(const half8*)&Al[idx];
    }
#pragma unroll
    for (int ct = 0; ct < 4; ++ct) {
      int idx = buf*4096 + ((ch*4 + ct)*64 + q*16 + n)*8;
      bf[ct][0] = *(const half8*)&Bh[idx];
      bf[ct][1] = *(const half8*)&Bl[idx];
    }
#pragma unroll
    for (int rt = 0; rt < 4; ++rt)
#pragma unroll
      for (int ct = 0; ct < 4; ++ct) {
        acc[rt][ct] = mfmaF16(af[rt][0], bf[ct][0], acc[rt][ct]);
        acc[rt][ct] = mfmaF16(af[rt][0], bf[ct][1], acc[rt][ct]);
        acc[rt][ct] = mfmaF16(af[rt][1], bf[ct][0], acc[rt][ct]);
      }
    __syncthreads();
  }

#pragma unroll
  for (int pass = 0; pass < 2; ++pass) {
    u16* dst = pass ? xql : xqh;
#pragma unroll
    for (int rt = 0; rt < 4; ++rt)
#pragma unroll
      for (int ct = 0; ct < 4; ++ct)
#pragma unroll
        for (int reg = 0; reg < 4; ++reg) {
          u16 hs, ls; split16(acc[rt][ct][reg], hs, ls);
          int ol = rh*64 + rt*16 + q*4 + reg;
          int pl = ch*64 + ct*16 + n;
          SM[ol*136 + pl] = pass ? ls : hs;
        }
    __syncthreads();
#pragma unroll
    for (int s = 0; s < 8; ++s) {
      int cc = tid*8 + s;
      int o = cc >> 4, p8 = cc & 15;
      ushort8 v = *(const ushort8*)&SM[o*136 + p8*8];
      *(ushort8*)(dst + ((long)b*TOKD + obase + o)*NVIS + pbase + p8*8) = v;
    }
    __syncthreads();
  }
}

// ================= retile: in-place row-major -> MFMA-fragment-tiled =================
__global__ __launch_bounds__(256)
void retile(u16* __restrict__ bufH, u16* __restrict__ bufL) {
  __shared__ u16 T[96*136] __attribute__((aligned(16)));
  const long tile = blockIdx.x;
  const int tid = threadIdx.x;
#pragma unroll
  for (int pass = 0; pass < 2; ++pass) {
    u16* buf = pass ? bufL : bufH;
    if (pass) __syncthreads();
#pragma unroll
    for (int i = 0; i < 6; ++i) {
      int g = i*256 + tid;
      int row = g / 96, c16 = g % 96;
      ushort8 v = *(const ushort8*)(buf + tile*12288 + row*768 + c16*8);
      *(ushort8*)&T[c16*136 + row*8] = v;
    }
    __syncthreads();
#pragma unroll
    for (int i = 0; i < 6; ++i) {
      int g = i*256 + tid;
      int kc = g >> 6, lp = g & 63;
      int q = lp >> 4, n = lp & 15;
      ushort8 v = *(const ushort8*)&T[(kc*4 + q)*136 + n*8];
      *(ushort8*)(buf + tile*12288 + (long)kc*512 + lp*8) = v;
    }
  }
}

// ================= VQ: A direct-to-register (plain loads), B via LDS (4-deep) ==============
// Round-3 counters: LDS was the binding pipe (~1536 cyc reads+writes vs MFMA ~1319 per
// 256-MFMA CU-round). Fix: wave tile 64 rows x 128 codes -> each A-frag consumed by exactly
// one wave, so A skips LDS: plain C++ half8 loads (compiler-tracked, auto-waitcnt; the
// round-0-verified mechanism), 2-deep named sets Aa/Ab. B (shared by 4 waves) via
// global_load_lds into 4-deep 8KB bufs (16 KB total), counted vmcnt + one raw barrier/iter.
// vmcnt invariant is region-structural: each iter region (bounded by "memory" asm) issues
// exactly 6 VMEM (2 B-DMA + 4 A); prologue drains to 0; so vmcnt(6) at region end completes
// exactly the PREVIOUS region's 6 (B(ht+1) publish + A(ht+1) landed) regardless of
// intra-region scheduling. Compiler adds its own (redundant, correct) waits for A before
// MFMA use. Buf reuse separated by two barriers as before.
// Per-CU-round budget now: LDS reads 32 ds_read_b128 x2blk ~770 cyc + 8KB DMA-write ~64 cyc
// < MFMA 1319 cyc -> MFMA is the binding pipe.
// Accumulation chain per element identical to rounds 0-3 (72-step hh/lh/hl order, same MFMA
// shape) -> bit-identical distances -> identical argmin.
__global__ __launch_bounds__(256, 2)
void vq_mfma(const u16* __restrict__ xqh, const u16* __restrict__ xql,
             const u16* __restrict__ cbh, const u16* __restrict__ cbl,
             const float* __restrict__ cbn, unsigned long long* __restrict__ keys) {
  __shared__ u16 SM[16384] __attribute__((aligned(16)));   // 32 KB: B[4][4096 u16]
  const int bid = blockIdx.x;
  const int xcd = bid & 7, slot = bid >> 3;          // slot 0..255
  const int rowBlk = xcd * 16 + (slot >> 4);         // 0..127 (16 per XCD)
  const int codeBlk = slot & 15;                     // 0..15, fastest-cycling within XCD
  const int rowTile0 = rowBlk * 16;                  // of 2048 row-tiles (16 rows each)
  const int codeTile0 = codeBlk * 8;                 // of 128 code-tiles
  const int tid = threadIdx.x, lane = tid & 63, w = tid >> 6;   // w in 0..3
  const int n = lane & 15, q = lane >> 4;

  // wave w owns row-tiles {rowTile0+4w .. +3} (64 rows) x all 8 code-tiles (128 codes)
  const u16* paH = xqh + (size_t)(rowTile0 + 4*w) * 12288 + lane*8;
  const u16* paL = xql + (size_t)(rowTile0 + 4*w) * 12288 + lane*8;
  // B staging: wave w stages code-tiles {2w, 2w+1} (2 KB) per iter
  const size_t bOff = (size_t)(codeTile0 + 2*w) * 12288 + lane*8;
  const int bChunk = (2*w)*512 + lane*8;             // u16 units within a 4096-u16 buffer

  auto STAGE_B = [&](int ht, int buf) {
    const int kk = ht - ((ht >= 48) ? 48 : ((ht >= 24) ? 24 : 0));
    const u16* pb = ((ht >= 48) ? cbl : cbh) + bOff + kk*512;
    u16* lb = &SM[buf*4096 + bChunk];
    __builtin_amdgcn_global_load_lds((AS1 void*)pb,           (AS3 void*)lb,         16, 0, 0);
    __builtin_amdgcn_global_load_lds((AS1 void*)(pb + 12288), (AS3 void*)(lb + 512), 16, 0, 0);
  };

  auto LOAD_A = [&](int ht, half8 (&R)[4]) {
    const int sA = (ht >= 24 && ht < 48);
    const int kA = ht - ((ht >= 48) ? 48 : (sA ? 24 : 0));
    const u16* pa_ = (sA ? paL : paH) + kA*512;
#pragma unroll
    for (int i = 0; i < 4; ++i) R[i] = *(const half8*)(pa_ + (size_t)i*12288);
  };

  f32x4 acc[4][8];
#pragma unroll
  for (int a = 0; a < 4; ++a)
#pragma unroll
    for (int b2 = 0; b2 < 8; ++b2) acc[a][b2] = (f32x4){0.f, 0.f, 0.f, 0.f};

  half8 Aa[4], Ab[4];

  // prologue: issue A(0),B(0),A(1),B(1); full drain (one-time); publish.
  LOAD_A(0, Aa); STAGE_B(0, 0);
  LOAD_A(1, Ab); STAGE_B(1, 1);
  asm volatile("s_waitcnt vmcnt(0)" ::: "memory");
  asm volatile("s_barrier" ::: "memory");

#define VQ_ITER(HT, CUR)                                                     \
  {                                                                          \
    const int ht_ = (HT);                                                    \
    const int pf_ = (ht_ + 2 > 71) ? 71 : ht_ + 2;                           \
    STAGE_B(pf_, (ht_ + 2) & 3);                                             \
    half8 Bf[8];                                                             \
    const int bb = (ht_ & 3)*4096 + lane*8;                                  \
    _Pragma("unroll")                                                        \
    for (int ct = 0; ct < 8; ++ct) Bf[ct] = *(const half8*)&SM[bb + ct*512]; \
    __builtin_amdgcn_s_setprio(1);                                           \
    _Pragma("unroll")                                                        \
    for (int rt = 0; rt < 4; ++rt)                                           \
      _Pragma("unroll")                                                      \
      for (int ct = 0; ct < 8; ++ct)                                         \
        acc[rt][ct] = mfmaF16(CUR[rt], Bf[ct], acc[rt][ct]);                 \
    __builtin_amdgcn_s_setprio(0);                                           \
    LOAD_A(pf_, CUR);                 /* CUR dead after MFMA; reload ht+2 */ \
    asm volatile("s_waitcnt vmcnt(6)" ::: "memory"); /* prev region's 6 */   \
    asm volatile("s_barrier" ::: "memory");          /* publish B(ht+1) */   \
  }

#pragma unroll 1
  for (int h2 = 0; h2 < 36; ++h2) {
    VQ_ITER(2*h2,     Aa);
    VQ_ITER(2*h2 + 1, Ab);
  }
#undef VQ_ITER

  // argmin epilogue: lane holds (row = (rowTile0+4w+rt)*16 + q*4 + reg, code = ct*16 + n)
  float cbv[8];
#pragma unroll
  for (int ct = 0; ct < 8; ++ct) cbv[ct] = cbn[(codeTile0 + ct)*16 + n];
#pragma unroll
  for (int rt = 0; rt < 4; ++rt) {
#pragma unroll
    for (int reg = 0; reg < 4; ++reg) {
      float bd = 3.4e38f; int bi = 0;
#pragma unroll
      for (int ct = 0; ct < 8; ++ct) {
        float d = cbv[ct] - 2.0f * acc[rt][ct][reg];
        int code = (codeTile0 + ct)*16 + n;
        if (d < bd) { bd = d; bi = code; }
      }
      unsigned long long k = pack_key(bd, bi);
      unsigned long long v;
      v = __shfl_xor(k, 1); k = (v < k) ? v : k;
      v = __shfl_xor(k, 2); k = (v < k) ? v : k;
      v = __shfl_xor(k, 4); k = (v < k) ? v : k;
      v = __shfl_xor(k, 8); k = (v < k) ? v : k;
      if (n == 0) {
        int row = (rowTile0 + 4*w + rt)*16 + q*4 + reg;
        atomicMin(&keys[row], k);
      }
    }
  }
}

// ================= fused gate + tail output (+ index unpack folded in) =================
__global__ __launch_bounds__(256)
void fuse_out(const float* __restrict__ src, const unsigned long long* __restrict__ keys,
              const float* __restrict__ gA, const float* __restrict__ uvec,
              const float* __restrict__ Mm, const float* __restrict__ tailcode,
              float* __restrict__ out, float* __restrict__ outIdx) {
  __shared__ float ss[32][257];
  __shared__ float s0s[32];
  __shared__ int ids[32];
  const int tid = threadIdx.x;
  const int rb = blockIdx.x * 32;
  const int b = rb >> 10;
  const int p0 = rb & 1023;
#pragma unroll
  for (int qq = 0; qq < 32; ++qq)
    ss[qq][tid] = src[(long)(p0 + qq) * (BSZ*HID) + b*HID + tid];
  if (tid < 32) {
    unsigned long long u = keys[rb + tid];
    int id = (int)(unsigned int)(u & 0xFFFFFFFFull);
    ids[tid] = id;
    outIdx[rb + tid] = (float)id;
  }
  __syncthreads();
  {
    const int wv = tid >> 6, lane = tid & 63;
    for (int qq = 0; qq < 8; ++qq) {
      int qp = wv*8 + qq;
      float a0 = 0.f, a1 = 0.f;
#pragma unroll
      for (int i = 0; i < 4; ++i) {
        float v = ss[qp][lane + 64*i];
        a0 += v * uvec[lane + 64*i];
        a1 += v * uvec[HID + lane + 64*i];
      }
#pragma unroll
      for (int off = 32; off; off >>= 1) { a0 += __shfl_down(a0, off); a1 += __shfl_down(a1, off); }
      if (lane == 0) {
        int id = ids[qp];
        float l0 = gA[id] + a0;
        float l1 = gA[NCODE + id] + a1;
        s0s[qp] = 1.0f / (1.0f + expf(l1 - l0));
      }
    }
  }
  __syncthreads();
  const int qg = tid >> 5, cg = tid & 31;
  const int q0 = qg * 4, c0 = cg * 8;
  float acc[4][8] = {};
  for (int cp = 0; cp < HID; ++cp) {
    float4 m0 = *(const float4*)(Mm + cp*HID + c0);
    float4 m1 = *(const float4*)(Mm + cp*HID + c0 + 4);
    float mm[8] = {m0.x,m0.y,m0.z,m0.w,m1.x,m1.y,m1.z,m1.w};
#pragma unroll
    for (int i = 0; i < 4; ++i) {
      float sv = ss[q0+i][cp];
#pragma unroll
      for (int j = 0; j < 8; ++j) acc[i][j] += sv * mm[j];
    }
  }
#pragma unroll
  for (int i = 0; i < 4; ++i) {
    int qp = q0 + i;
    int id = ids[qp];
    float s0 = s0s[qp], s1 = 1.0f - s0;
    const float* tc = tailcode + (long)id*HID + c0;
    float* op = out + (long)(p0+qp)*(BSZ*HID) + b*HID + c0;
    float4 o0, o1;
    o0.x = s0*tc[0] + s1*acc[i][0]; o0.y = s0*tc[1] + s1*acc[i][1];
    o0.z = s0*tc[2] + s1*acc[i][2]; o0.w = s0*tc[3] + s1*acc[i][3];
    o1.x = s0*tc[4] + s1*acc[i][4]; o1.y = s0*tc[5] + s1*acc[i][5];
    o1.z = s0*tc[6] + s1*acc[i][6]; o1.w = s0*tc[7] + s1*acc[i][7];
    *(float4*)(op) = o0; *(float4*)(op+4) = o1;
  }
}

// ================= launch =================
extern "C" void kernel_launch(void* const* d_in, const int* in_sizes, int n_in,
                              void* d_out, int out_size, void* d_ws, size_t ws_size,
                              hipStream_t stream) {
  const float* src    = (const float*)d_in[0];
  const float* cb     = (const float*)d_in[1];
  const float* w_head = (const float*)d_in[2];
  const float* w_tail = (const float*)d_in[3];
  const float* w_pos  = (const float*)d_in[4];
  const float* b_pos  = (const float*)d_in[5];
  const float* w_gate = (const float*)d_in[6];
  float* out = (float*)d_out;

  char* wsp = (char*)d_ws;
  size_t off = 0;
  auto alloc = [&](size_t bytes) {
    off = (off + 255) & ~(size_t)255;
    void* p = wsp + off; off += bytes; return p;
  };
  u16* xqh = (u16*)alloc((size_t)BSZ*TOKD*NVIS*2);  // 50.3 MB
  u16* xql = (u16*)alloc((size_t)BSZ*TOKD*NVIS*2);  // 50.3 MB
  u16* cbh = (u16*)alloc((size_t)NCODE*TOKD*2);
  u16* cbl = (u16*)alloc((size_t)NCODE*TOKD*2);
  u16* whh = (u16*)alloc((size_t)TOKD*HID*2);
  u16* whl = (u16*)alloc((size_t)TOKD*HID*2);
  float* cbn      = (float*)alloc((size_t)NCODE*4);
  float* Gt       = (float*)alloc((size_t)TOKD*HID*4);
  float* g2       = (float*)alloc((size_t)2*TOKD*4);
  float* ct0      = (float*)alloc((size_t)HID*4);
  float* cg       = (float*)alloc((size_t)2*4);
  float* tailcode = (float*)alloc((size_t)NCODE*HID*4);
  float* gA       = (float*)alloc((size_t)2*NCODE*4);
  float* Mm       = (float*)alloc((size_t)HID*HID*4);
  float* uvec     = (float*)alloc((size_t)2*HID*4);
  unsigned long long* keys = (unsigned long long*)alloc((size_t)NPIX*8);
  (void)ws_size; (void)in_sizes; (void)n_in; (void)out_size;

  prep1<<<8455, 256, 0, stream>>>(cb, w_head, w_tail, w_pos, w_gate, b_pos,
                                  cbh, cbl, whh, whl, cbn, Mm, uvec, Gt, g2, ct0, cg);
  retile<<<NCODE/16, 256, 0, stream>>>(cbh, cbl);          // codebook -> frag-tiled
  prep2<<<NCODE/8, 256, 0, stream>>>(cb, Gt, ct0, g2, cg, tailcode, gA);

  head_mfma<<<dim3(TOKD/128, NVIS/128, BSZ), 256, 0, stream>>>(whh, whl, src, xqh, xql);
  retile<<<NPIX/16, 256, 0, stream>>>(xqh, xql);           // xq -> frag-tiled (in place)

  hipMemsetAsync(keys, 0xFF, (size_t)NPIX*8, stream);
  vq_mfma<<<2048, 256, 0, stream>>>(xqh, xql, cbh, cbl, cbn, keys);

  fuse_out<<<NPIX/32, 256, 0, stream>>>(src, keys, gA, uvec, Mm, tailcode,
                                        out, out + (size_t)NVIS*BSZ*HID);
}